// Round 10
// baseline (287.979 us; speedup 1.0000x reference)
//
#include <hip/hip_runtime.h>
#include <hip/hip_bf16.h>
#include <math.h>

// D=4096 K=512 HOP=512 WIN=16384 DX=25 B=128 K2=128 DY=128 K3=256 Y=193 M=128
// ws layout (bytes):
//   zxb  @ 0          : 128*25*512*2   = 3,276,800   (bf16 zx)
//   h2b  @ 3,276,800  : 128*256*193*2  = 12,644,352  (bf16 h2)
//   w1b  @ 15,921,152 : 32,768                      (bf16 w1 [k2][dy])
//   w2c  @ 15,953,920 : 1,638,400                   (bf16 w2 [k3][dx*128+k2])
//   bb   @ 17,592,320 : 128*49408*2    = 12,648,448 (bf16 beta)
//   xh   @ 30,240,768 : 128*16384*2    = 4,194,304  (fp16 x)       } dead after K1
//   fB   @ 34,435,072 : 4096*1024*2    = 8,388,608  (fp16 filt)    }
//   part @ 30,240,768 : 193*16384*4    = 12,648,448 (aliases xh/fB; used after K1)

typedef __attribute__((ext_vector_type(8))) short s8v;       // 8 bf16
typedef __attribute__((ext_vector_type(8))) _Float16 half8;  // 8 fp16
typedef __attribute__((ext_vector_type(16))) float f16v;     // 32x32 acc

__device__ inline ushort f2bf(float f) {
    union { float f; unsigned u; } v; v.f = f;
    unsigned u = v.u;
    return (ushort)((u + 0x7FFFu + ((u >> 16) & 1u)) >> 16);
}

// ---------------- K0all v2: vectorized prep, one grid-stride launch ------
#define K0_E0 262144
#define K0_E1 786432
#define K0_E2 788480
#define K0_E3 1607680
#define K0_E4 2398208
__global__ __launch_bounds__(256)
void k0all(const float* __restrict__ x, const float* __restrict__ filt,
           const float* __restrict__ w1, const float* __restrict__ w2,
           const float* __restrict__ beta,
           _Float16* __restrict__ xh, _Float16* __restrict__ fB,
           ushort* __restrict__ w1b, ushort* __restrict__ w2c,
           ushort* __restrict__ bb) {
    for (int i = blockIdx.x * 256 + threadIdx.x; i < K0_E4; i += gridDim.x * 256) {
        if (i < K0_E0) {
            int o = i * 8;
            float4 f0 = *(const float4*)(x + o);
            float4 f1 = *(const float4*)(x + o + 4);
            half8 v;
            v[0] = (_Float16)f0.x; v[1] = (_Float16)f0.y;
            v[2] = (_Float16)f0.z; v[3] = (_Float16)f0.w;
            v[4] = (_Float16)f1.x; v[5] = (_Float16)f1.y;
            v[6] = (_Float16)f1.z; v[7] = (_Float16)f1.w;
            *(half8*)(xh + o) = v;
        } else if (i < K0_E1) {
            int o = i - K0_E0;                 // 0..524287
            int kc8 = o >> 10, nn = o & 1023;
            const float* fp = filt + (size_t)(kc8 * 8) * 1024 + nn;
            half8 v;
#pragma unroll
            for (int j = 0; j < 8; j++) v[j] = (_Float16)fp[(size_t)j * 1024];
            *(half8*)(fB + (size_t)o * 8) = v;
        } else if (i < K0_E2) {
            int o = (i - K0_E1) * 8;
            float4 f0 = *(const float4*)(w1 + o);
            float4 f1 = *(const float4*)(w1 + o + 4);
            s8v v;
            v[0] = (short)f2bf(f0.x); v[1] = (short)f2bf(f0.y);
            v[2] = (short)f2bf(f0.z); v[3] = (short)f2bf(f0.w);
            v[4] = (short)f2bf(f1.x); v[5] = (short)f2bf(f1.y);
            v[6] = (short)f2bf(f1.z); v[7] = (short)f2bf(f1.w);
            *(s8v*)(w1b + o) = v;
        } else if (i < K0_E3) {
            int o = i - K0_E2;                 // 0..819199
            int k2 = o & 127;
            int dx = (o >> 7) % 25;
            int k3 = o / 3200;
            w2c[o] = f2bf(w2[(k3 * 128 + k2) * 25 + dx]);
        } else {
            int o = (i - K0_E3) * 8;
            float4 f0 = *(const float4*)(beta + o);
            float4 f1 = *(const float4*)(beta + o + 4);
            s8v v;
            v[0] = (short)f2bf(f0.x); v[1] = (short)f2bf(f0.y);
            v[2] = (short)f2bf(f0.z); v[3] = (short)f2bf(f0.w);
            v[4] = (short)f2bf(f1.x); v[5] = (short)f2bf(f1.y);
            v[6] = (short)f2bf(f1.z); v[7] = (short)f2bf(f1.w);
            *(s8v*)(bb + o) = v;
        }
    }
}

// ---------------- K1: spec GEMM via fp16 MFMA + |.|^2 + log -> zxb ----------------
// v5: v3's raw-barrier + distance-2 prefetch scheme with BK=64 phases:
// 64 phases (was 128), 32 MFMAs/phase (was 16), half the barriers, same
// per-phase structure. LDS 2x16KB (irrelevant at 1 block/CU, grid 200).
// Accumulation order ko-ascending -> bit-identical to v3.
// Do NOT go barrier-free per-lane-A (r8: +62us uncoalesced scatter).
#define K1Q(KB, LP, VU, VL, RL, RW, DOPREF, DOWRITE)                               \
  {                                                                                \
    asm volatile("s_waitcnt lgkmcnt(0)" ::: "memory");                             \
    __builtin_amdgcn_s_barrier();                                                  \
    asm volatile("" ::: "memory");                                                 \
    if (DOPREF) {                                                                  \
      _Pragma("unroll")                                                            \
      for (int j = 0; j < 4; j++) {                                                \
        RL[j] = *(const half8*)(apt + ((KB) + 2) * 64 + j * 16);                   \
        const _Float16* pBk = pB + ((size_t)(((KB) + 2) * 4 + j)) * 16384;         \
        VL[j][0] = *(const half8*)(pBk);                                           \
        VL[j][1] = *(const half8*)(pBk + 256);                                     \
      }                                                                            \
    }                                                                              \
    _Pragma("unroll")                                                              \
    for (int s = 0; s < 4; s++) {                                                  \
      half8 a0 = *(const half8*)((const char*)Al + (LP) * 16384 + s * 4096 +       \
                                 (wm + ml) * 32 + qf * 16);                        \
      half8 a1 = *(const half8*)((const char*)Al + (LP) * 16384 + s * 4096 +       \
                                 (wm + 32 + ml) * 32 + qf * 16);                   \
      acc[0][0] = __builtin_amdgcn_mfma_f32_32x32x16_f16(a0, VU[s][0], acc[0][0], 0, 0, 0); \
      acc[0][1] = __builtin_amdgcn_mfma_f32_32x32x16_f16(a0, VU[s][1], acc[0][1], 0, 0, 0); \
      acc[1][0] = __builtin_amdgcn_mfma_f32_32x32x16_f16(a1, VU[s][0], acc[1][0], 0, 0, 0); \
      acc[1][1] = __builtin_amdgcn_mfma_f32_32x32x16_f16(a1, VU[s][1], acc[1][1], 0, 0, 0); \
    }                                                                              \
    if (DOWRITE) {                                                                 \
      char* dnx = (char*)Al + (1 - (LP)) * 16384;                                  \
      _Pragma("unroll")                                                            \
      for (int j = 0; j < 4; j++)                                                  \
        *(half8*)(dnx + j * 4096 + t * 16) = RW[j];                                \
    }                                                                              \
  }

__global__ __launch_bounds__(256)
void k1_mfma(const _Float16* __restrict__ xh, const _Float16* __restrict__ fB,
             ushort* __restrict__ zxb) {
    __shared__ _Float16 Al[2][8192];   // 32 KB, double-buffered, BK=64
    const int t  = threadIdx.x;
    const int n0 = blockIdx.y * 128;
    const int m0 = blockIdx.x * 128;
    const int w  = t >> 6, l = t & 63;
    const int wm = (w >> 1) * 64, wn = (w & 1) * 64;
    const int qf = l >> 5;
    const int ml = l & 31;

    const int srow = t >> 1;
    const int sq   = t & 1;
    const int gm   = m0 + srow;
    const _Float16* apt = xh + (gm / 25) * 16384 + (gm % 25) * 512 + sq * 8;

    const _Float16* pB = fB + ((size_t)qf * 1024 + (size_t)(n0 + wn + ml)) * 8;

    f16v acc[2][2];
#pragma unroll
    for (int i = 0; i < 2; i++)
#pragma unroll
        for (int j = 0; j < 2; j++)
#pragma unroll
            for (int r = 0; r < 16; r++) acc[i][j][r] = 0.f;

    half8 vb0[4][2], vb1[4][2], vb2[4][2], vb3[4][2];
    half8 rA0[4], rA1[4];

    // ---- prologue: A(0) -> LDS[0]; A(1) -> rA1; B(0) -> vb0; B(1) -> vb1 ----
    {
#pragma unroll
        for (int j = 0; j < 4; j++) {
            half8 v = *(const half8*)(apt + j * 16);
            *(half8*)((char*)Al + j * 4096 + t * 16) = v;
            rA1[j] = *(const half8*)(apt + 64 + j * 16);
            const _Float16* pBk0 = pB + (size_t)j * 16384;
            vb0[j][0] = *(const half8*)(pBk0);
            vb0[j][1] = *(const half8*)(pBk0 + 256);
            const _Float16* pBk1 = pB + (size_t)(4 + j) * 16384;
            vb1[j][0] = *(const half8*)(pBk1);
            vb1[j][1] = *(const half8*)(pBk1 + 256);
        }
    }

    // ---- main: phases 0..59 (period-4 buffer rotation, prefetch valid) ----
    for (int it = 0; it < 15; it++) {
        const int kb = it * 4;
        K1Q(kb + 0, 0, vb0, vb2, rA0, rA1, true, true)
        K1Q(kb + 1, 1, vb1, vb3, rA1, rA0, true, true)
        K1Q(kb + 2, 0, vb2, vb0, rA0, rA1, true, true)
        K1Q(kb + 3, 1, vb3, vb1, rA1, rA0, true, true)
    }
    // ---- epilogue: phases 60..63 ----
    K1Q(60, 0, vb0, vb2, rA0, rA1, true, true)
    K1Q(61, 1, vb1, vb3, rA1, rA0, true, true)
    K1Q(62, 0, vb2, vb0, rA0, rA1, false, true)
    K1Q(63, 1, vb3, vb1, rA1, rA0, false, false)

#pragma unroll
    for (int mt = 0; mt < 2; mt++)
#pragma unroll
        for (int nt = 0; nt < 2; nt++) {
#pragma unroll
            for (int r = 0; r < 16; r++) {
                float val = acc[mt][nt][r];
                float oth = __shfl_xor(val, 1, 64);
                if (!(l & 1)) {
                    float pw = fmaf(val, val, fmaf(oth, oth, 1e-14f));
                    int m = m0 + wm + mt * 32 + 4 * qf + (r & 3) + 8 * (r >> 2);
                    int n = n0 + wn + nt * 32 + ml;
                    zxb[m * 512 + (n >> 1)] = f2bf(logf(pw));
                }
            }
        }
}

// ---------------- K2: fused conv1+conv2, chunked-dx (3), y-tile 64 ----------------
// grid (4 yt, 128 b), 4 waves. LDS: zl dbuf (2x3dx x 4 copies x 272) + h1l (3dx).
// PROVEN 137.4 us version (round-0/2/5/7/9): (256,2), w1b input, plain conv2 loop.
// FROZEN. Do NOT hand-pipeline conv2 regs (r6: -20us), split waves/tiles
// (r1/r3: -90us), or bundle bounds/setprio/w1-fold (r4: -10us).
#define ZPITCH 272
__global__ __launch_bounds__(256, 2)
void k2_mfma(const ushort* __restrict__ zxb, const ushort* __restrict__ w1b,
             const ushort* __restrict__ w2c, ushort* __restrict__ h2b) {
    __shared__ ushort zl[2 * 3 * 4 * ZPITCH];   // 13,056 B
    __shared__ ushort h1l[3 * 16 * 64 * 8];     // 49,152 B
    const int t  = threadIdx.x;
    const int yt = blockIdx.x;      // 0..3
    const int b  = blockIdx.y;
    const int y0 = yt * 64;
    const int w  = t >> 6;
    const int l  = t & 63;
    const int yy = l & 31;
    const int q  = l >> 5;

    // persistent conv1 A-frags (w1): wave w owns k2 in [32w, 32w+32)
    s8v w1f[8];
    {
        const ushort* wp = w1b + (32 * w + yy) * 128 + 8 * q;
#pragma unroll
        for (int ks = 0; ks < 8; ks++)
            w1f[ks] = *(const s8v*)(wp + 16 * ks);
    }

    f16v acc[2][2];
#pragma unroll
    for (int mt = 0; mt < 2; mt++)
#pragma unroll
        for (int nt = 0; nt < 2; nt++)
#pragma unroll
            for (int r = 0; r < 16; r++) acc[mt][nt][r] = 0.f;

    // ---- initial stage: chunk 0 -> buf 0 ----
    {
        const int nq = 3 * 4 * 62;
        for (int idx = t; idx < nq; idx += 256) {
            int iq = idx % 62;
            int dc = idx / 62;
            int c = dc & 3, d = dc >> 2;
            const ushort* src = zxb + ((b * 25 + d) << 9);
            int gg = 2 * y0 + 2 * c + 4 * iq;
            ushort* dst = zl + (d * 4 + c) * ZPITCH + 4 * iq;
#pragma unroll
            for (int u = 0; u < 4; u++) {
                int g = gg + u;
                dst[u] = (g < 512) ? src[g] : (ushort)0;
            }
        }
    }

    for (int ch = 0; ch < 9; ch++) {
        const int p  = ch & 1;
        const int nd = (ch == 8) ? 1 : 3;
        __syncthreads();   // zl[p] staged, h1l free (prev conv2 done)

        // ---- prefetch loads for chunk ch+1 into regs ----
        ushort pv[12];
        int nq2 = 0;
        if (ch < 8) {
            const int nd2 = (ch == 7) ? 1 : 3;
            nq2 = nd2 * 4 * 62;
#pragma unroll
            for (int r = 0; r < 3; r++) {
                int idx = t + r * 256;
                if (idx < nq2) {
                    int iq = idx % 62;
                    int dc = idx / 62;
                    int c = dc & 3, d = dc >> 2;
                    const ushort* src = zxb + ((b * 25 + (ch + 1) * 3 + d) << 9);
                    int gg = 2 * y0 + 2 * c + 4 * iq;
#pragma unroll
                    for (int u = 0; u < 4; u++) {
                        int g = gg + u;
                        pv[r * 4 + u] = (g < 512) ? src[g] : (ushort)0;
                    }
                }
            }
        }

        // ---- conv1: h1[d][k2][ye] for this chunk ----
        for (int d = 0; d < nd; d++) {
            const int zb = (p * 3 + d) * 4;
#pragma unroll
            for (int nt = 0; nt < 2; nt++) {
                const int ye = nt * 32 + yy;
                const ushort* zp = zl + (zb + (ye & 3)) * ZPITCH + 8 * (ye >> 2) + 8 * q;
                f16v a1;
#pragma unroll
                for (int r = 0; r < 16; r++) a1[r] = 0.f;
#pragma unroll
                for (int ks = 0; ks < 8; ks++) {
                    s8v bf = *(const s8v*)(zp + 16 * ks);
                    a1 = __builtin_amdgcn_mfma_f32_32x32x16_bf16(w1f[ks], bf, a1, 0, 0, 0);
                }
                // relu + pack: k2 = 32w + 8g + 4q + r  -> h1l[d][4w+g][ye][4q+r]
#pragma unroll
                for (int g = 0; g < 4; g++) {
                    unsigned p0 = (unsigned)f2bf(fmaxf(a1[4 * g + 0], 0.f))
                                | ((unsigned)f2bf(fmaxf(a1[4 * g + 1], 0.f)) << 16);
                    unsigned p1 = (unsigned)f2bf(fmaxf(a1[4 * g + 2], 0.f))
                                | ((unsigned)f2bf(fmaxf(a1[4 * g + 3], 0.f)) << 16);
                    unsigned* dst = (unsigned*)(h1l + (((d * 16 + 4 * w + g) * 64) + ye) * 8 + 4 * q);
                    dst[0] = p0; dst[1] = p1;
                }
            }
        }

        // ---- write prefetched zl[1-p] ----
        if (ch < 8) {
#pragma unroll
            for (int r = 0; r < 3; r++) {
                int idx = t + r * 256;
                if (idx < nq2) {
                    int iq = idx % 62;
                    int dc = idx / 62;
                    int c = dc & 3, d = dc >> 2;
                    ushort* dst = zl + (((1 - p) * 3 + d) * 4 + c) * ZPITCH + 4 * iq;
#pragma unroll
                    for (int u = 0; u < 4; u++) dst[u] = pv[r * 4 + u];
                }
            }
        }

        __syncthreads();   // h1l ready

        // ---- conv2: acc[mt][nt] += w2[k3][dx,k2] * h1 ----
        for (int d = 0; d < nd; d++) {
            const int dxa = ch * 3 + d;
            const ushort* ap = w2c + (size_t)(64 * w + yy) * 3200 + dxa * 128 + 8 * q;
#pragma unroll
            for (int ks = 0; ks < 8; ks++) {
                s8v a0 = *(const s8v*)(ap + 16 * ks);
                s8v a1f = *(const s8v*)(ap + (size_t)32 * 3200 + 16 * ks);
#pragma unroll
                for (int nt = 0; nt < 2; nt++) {
                    s8v hb = *(const s8v*)(h1l + (((d * 16 + 2 * ks + q) * 64) + nt * 32 + yy) * 8);
                    acc[0][nt] = __builtin_amdgcn_mfma_f32_32x32x16_bf16(a0, hb, acc[0][nt], 0, 0, 0);
                    acc[1][nt] = __builtin_amdgcn_mfma_f32_32x32x16_bf16(a1f, hb, acc[1][nt], 0, 0, 0);
                }
            }
        }
    }

    // ---- epilogue: store h2b (relu) ----
#pragma unroll
    for (int mt = 0; mt < 2; mt++)
#pragma unroll
        for (int nt = 0; nt < 2; nt++) {
            int y = y0 + nt * 32 + yy;
            if (y < 193) {
#pragma unroll
                for (int r = 0; r < 16; r++) {
                    int k3 = 64 * w + 32 * mt + (r & 3) + 8 * (r >> 2) + 4 * q;
                    h2b[(b * 256 + k3) * 193 + y] = f2bf(fmaxf(acc[mt][nt][r], 0.f));
                }
            }
        }
}

// ---------------- K4: y partials via bf16 MFMA, 193-way k-split ----------------
// ks loop unrolled 4x: 20 independent L2 loads in flight per batch (1 block/CU,
// latency-bound regime -> ILP from unroll is free).
__global__ __launch_bounds__(256)
void k4_mfma(const ushort* __restrict__ h2b, const ushort* __restrict__ bb,
             float* __restrict__ part) {
    const int t = threadIdx.x, w = t >> 6, l = t & 63;
    const int s = blockIdx.x;
    const int kb = s * 256;
    const int qf = l >> 5;
    const int ml = l & 31;
    const ushort* pa  = h2b + (size_t)(w * 32 + ml) * 49408 + kb + qf * 8;
    const ushort* pb0 = bb  + (size_t)ml * 49408 + kb + qf * 8;

    f16v acc[4];
#pragma unroll
    for (int nt = 0; nt < 4; nt++)
#pragma unroll
        for (int r = 0; r < 16; r++) acc[nt][r] = 0.f;

#pragma unroll 4
    for (int ks = 0; ks < 16; ks++) {
        s8v af = *(const s8v*)(pa + ks * 16);
#pragma unroll
        for (int nt = 0; nt < 4; nt++) {
            s8v bf = *(const s8v*)(pb0 + (size_t)nt * 32 * 49408 + ks * 16);
            acc[nt] = __builtin_amdgcn_mfma_f32_32x32x16_bf16(af, bf, acc[nt], 0, 0, 0);
        }
    }
    float* pp = part + (size_t)s * 16384;
#pragma unroll
    for (int nt = 0; nt < 4; nt++)
#pragma unroll
        for (int r = 0; r < 16; r++) {
            int m = w * 32 + 4 * qf + (r & 3) + 8 * (r >> 2);
            pp[m * 128 + nt * 32 + ml] = acc[nt][r];
        }
}

// ---------------- K5: reduce 193 partials (256 blocks, 4-way k-split) ----------------
__global__ __launch_bounds__(256)
void k5_red(const float* __restrict__ part, float* __restrict__ out) {
    __shared__ float red[256];
    const int t  = threadIdx.x;
    const int io = t & 63;
    const int kq = t >> 6;
    const int i  = blockIdx.x * 64 + io;
    float s = 0.f;
#pragma unroll 4
    for (int k = kq; k < 193; k += 4) s += part[(size_t)k * 16384 + i];
    red[t] = s;
    __syncthreads();
    if (t < 64)
        out[blockIdx.x * 64 + t] = (red[t] + red[t + 64]) + (red[t + 128] + red[t + 192]);
}

extern "C" void kernel_launch(void* const* d_in, const int* in_sizes, int n_in,
                              void* d_out, int out_size, void* d_ws, size_t ws_size,
                              hipStream_t stream) {
    const float* x    = (const float*)d_in[0];
    const float* filt = (const float*)d_in[1];
    const float* w1   = (const float*)d_in[2];
    const float* w2   = (const float*)d_in[3];
    const float* beta = (const float*)d_in[4];
    float* out = (float*)d_out;

    char* ws = (char*)d_ws;
    ushort*   zxb  = (ushort*)(ws + 0);
    ushort*   h2b  = (ushort*)(ws + 3276800);
    ushort*   w1b  = (ushort*)(ws + 15921152);
    ushort*   w2c  = (ushort*)(ws + 15953920);
    ushort*   bb   = (ushort*)(ws + 17592320);
    _Float16* xh   = (_Float16*)(ws + 30240768);
    _Float16* fB   = (_Float16*)(ws + 34435072);
    float*    part = (float*)(ws + 30240768);

    k0all<<<2048, 256, 0, stream>>>(x, filt, w1, w2, beta, xh, fB, w1b, w2c, bb);
    k1_mfma<<<dim3(25, 8), 256, 0, stream>>>(xh, fB, zxb);
    k2_mfma<<<dim3(4, 128), 256, 0, stream>>>(zxb, w1b, w2c, h2b);
    k4_mfma<<<193, 256, 0, stream>>>(h2b, bb, part);
    k5_red<<<256, 256, 0, stream>>>(part, out);
}

// Round 11
// 279.818 us; speedup vs baseline: 1.0292x; 1.0292x over previous
//
#include <hip/hip_runtime.h>
#include <hip/hip_bf16.h>
#include <math.h>

// D=4096 K=512 HOP=512 WIN=16384 DX=25 B=128 K2=128 DY=128 K3=256 Y=193 M=128
// ws layout (bytes):
//   zxb  @ 0          : 128*25*512*2   = 3,276,800   (bf16 zx)
//   h2b  @ 3,276,800  : 128*256*193*2  = 12,644,352  (bf16 h2)
//   w1b  @ 15,921,152 : 32,768                      (bf16 w1 [k2][dy])
//   w2c  @ 15,953,920 : 1,638,400                   (bf16 w2 [k3][dx*128+k2])
//   bb   @ 17,592,320 : 128*49408*2    = 12,648,448 (bf16 beta)
//   xh   @ 30,240,768 : 128*16384*2    = 4,194,304  (fp16 x)       } dead after K1
//   fB   @ 34,435,072 : 4096*1024*2    = 8,388,608  (fp16 filt)    }
//   part @ 30,240,768 : 193*16384*4    = 12,648,448 (aliases xh/fB; used after K1)

typedef __attribute__((ext_vector_type(8))) short s8v;       // 8 bf16
typedef __attribute__((ext_vector_type(8))) _Float16 half8;  // 8 fp16
typedef __attribute__((ext_vector_type(16))) float f16v;     // 32x32 acc

__device__ inline ushort f2bf(float f) {
    union { float f; unsigned u; } v; v.f = f;
    unsigned u = v.u;
    return (ushort)((u + 0x7FFFu + ((u >> 16) & 1u)) >> 16);
}

// ---------------- K0all v2: vectorized prep, one grid-stride launch ------
#define K0_E0 262144
#define K0_E1 786432
#define K0_E2 788480
#define K0_E3 1607680
#define K0_E4 2398208
__global__ __launch_bounds__(256)
void k0all(const float* __restrict__ x, const float* __restrict__ filt,
           const float* __restrict__ w1, const float* __restrict__ w2,
           const float* __restrict__ beta,
           _Float16* __restrict__ xh, _Float16* __restrict__ fB,
           ushort* __restrict__ w1b, ushort* __restrict__ w2c,
           ushort* __restrict__ bb) {
    for (int i = blockIdx.x * 256 + threadIdx.x; i < K0_E4; i += gridDim.x * 256) {
        if (i < K0_E0) {
            int o = i * 8;
            float4 f0 = *(const float4*)(x + o);
            float4 f1 = *(const float4*)(x + o + 4);
            half8 v;
            v[0] = (_Float16)f0.x; v[1] = (_Float16)f0.y;
            v[2] = (_Float16)f0.z; v[3] = (_Float16)f0.w;
            v[4] = (_Float16)f1.x; v[5] = (_Float16)f1.y;
            v[6] = (_Float16)f1.z; v[7] = (_Float16)f1.w;
            *(half8*)(xh + o) = v;
        } else if (i < K0_E1) {
            int o = i - K0_E0;                 // 0..524287
            int kc8 = o >> 10, nn = o & 1023;
            const float* fp = filt + (size_t)(kc8 * 8) * 1024 + nn;
            half8 v;
#pragma unroll
            for (int j = 0; j < 8; j++) v[j] = (_Float16)fp[(size_t)j * 1024];
            *(half8*)(fB + (size_t)o * 8) = v;
        } else if (i < K0_E2) {
            int o = (i - K0_E1) * 8;
            float4 f0 = *(const float4*)(w1 + o);
            float4 f1 = *(const float4*)(w1 + o + 4);
            s8v v;
            v[0] = (short)f2bf(f0.x); v[1] = (short)f2bf(f0.y);
            v[2] = (short)f2bf(f0.z); v[3] = (short)f2bf(f0.w);
            v[4] = (short)f2bf(f1.x); v[5] = (short)f2bf(f1.y);
            v[6] = (short)f2bf(f1.z); v[7] = (short)f2bf(f1.w);
            *(s8v*)(w1b + o) = v;
        } else if (i < K0_E3) {
            int o = i - K0_E2;                 // 0..819199
            int k2 = o & 127;
            int dx = (o >> 7) % 25;
            int k3 = o / 3200;
            w2c[o] = f2bf(w2[(k3 * 128 + k2) * 25 + dx]);
        } else {
            int o = (i - K0_E3) * 8;
            float4 f0 = *(const float4*)(beta + o);
            float4 f1 = *(const float4*)(beta + o + 4);
            s8v v;
            v[0] = (short)f2bf(f0.x); v[1] = (short)f2bf(f0.y);
            v[2] = (short)f2bf(f0.z); v[3] = (short)f2bf(f0.w);
            v[4] = (short)f2bf(f1.x); v[5] = (short)f2bf(f1.y);
            v[6] = (short)f2bf(f1.z); v[7] = (short)f2bf(f1.w);
            *(s8v*)(bb + o) = v;
        }
    }
}

// ---------------- K1: spec GEMM via fp16 MFMA + |.|^2 + log -> zxb ----------------
// v3 (PROVEN, part of 284.5 best): raw s_barrier with lgkmcnt(0) only, prefetch
// distance 2, B quad-buffered + A double-buffered in regs. BK=64 (v5, r10) was
// neutral; barrier-free per-lane A (v4, r8) was +62us (uncoalesced scatter).
#define K1P(KB, LP, VU, VL, RL, RW, DOPREF, DOWRITE)                               \
  {                                                                                \
    asm volatile("s_waitcnt lgkmcnt(0)" ::: "memory");                             \
    __builtin_amdgcn_s_barrier();                                                  \
    asm volatile("" ::: "memory");                                                 \
    if (DOPREF) {                                                                  \
      RL[0] = *(const half8*)(apt + ((KB) + 2) * 32);                              \
      RL[1] = *(const half8*)(apt + ((KB) + 2) * 32 + 16);                         \
      _Pragma("unroll")                                                            \
      for (int s = 0; s < 2; s++) {                                                \
        const _Float16* pBk = pB + ((size_t)((KB) + 2) * 2 + s) * 16384;           \
        VL[s][0] = *(const half8*)(pBk);                                           \
        VL[s][1] = *(const half8*)(pBk + 256);                                     \
      }                                                                            \
    }                                                                              \
    _Pragma("unroll")                                                              \
    for (int s = 0; s < 2; s++) {                                                  \
      half8 a0 = *(const half8*)((const char*)Al + (LP) * 8192 + s * 4096 +        \
                                 (wm + ml) * 32 + qf * 16);                        \
      half8 a1 = *(const half8*)((const char*)Al + (LP) * 8192 + s * 4096 +        \
                                 (wm + 32 + ml) * 32 + qf * 16);                   \
      acc[0][0] = __builtin_amdgcn_mfma_f32_32x32x16_f16(a0, VU[s][0], acc[0][0], 0, 0, 0); \
      acc[0][1] = __builtin_amdgcn_mfma_f32_32x32x16_f16(a0, VU[s][1], acc[0][1], 0, 0, 0); \
      acc[1][0] = __builtin_amdgcn_mfma_f32_32x32x16_f16(a1, VU[s][0], acc[1][0], 0, 0, 0); \
      acc[1][1] = __builtin_amdgcn_mfma_f32_32x32x16_f16(a1, VU[s][1], acc[1][1], 0, 0, 0); \
    }                                                                              \
    if (DOWRITE) {                                                                 \
      half8* dnx = (half8*)((char*)Al + (1 - (LP)) * 8192);                        \
      dnx[t] = RW[0];                                                              \
      dnx[256 + t] = RW[1];                                                        \
    }                                                                              \
  }

__global__ __launch_bounds__(256)
void k1_mfma(const _Float16* __restrict__ xh, const _Float16* __restrict__ fB,
             ushort* __restrict__ zxb) {
    __shared__ _Float16 Al[2][4096];   // 16 KB, double-buffered
    const int t  = threadIdx.x;
    const int n0 = blockIdx.y * 128;
    const int m0 = blockIdx.x * 128;
    const int w  = t >> 6, l = t & 63;
    const int wm = (w >> 1) * 64, wn = (w & 1) * 64;
    const int qf = l >> 5;
    const int ml = l & 31;

    const int srow = t >> 1;
    const int sq   = t & 1;
    const int gm   = m0 + srow;
    const _Float16* apt = xh + (gm / 25) * 16384 + (gm % 25) * 512 + sq * 8;

    const _Float16* pB = fB + ((size_t)qf * 1024 + (size_t)(n0 + wn + ml)) * 8;

    f16v acc[2][2];
#pragma unroll
    for (int i = 0; i < 2; i++)
#pragma unroll
        for (int j = 0; j < 2; j++)
#pragma unroll
            for (int r = 0; r < 16; r++) acc[i][j][r] = 0.f;

    half8 vb0[2][2], vb1[2][2], vb2[2][2], vb3[2][2];
    half8 rA0[2], rA1[2];

    // ---- prologue: A(0) -> LDS[0]; A(1) -> rA1; B(0) -> vb0; B(1) -> vb1 ----
    {
        rA0[0] = *(const half8*)(apt);
        rA0[1] = *(const half8*)(apt + 16);
        half8* d0 = (half8*)Al;
        d0[t] = rA0[0];
        d0[256 + t] = rA0[1];
        rA1[0] = *(const half8*)(apt + 32);
        rA1[1] = *(const half8*)(apt + 48);
#pragma unroll
        for (int s = 0; s < 2; s++) {
            const _Float16* pBk = pB + (size_t)s * 16384;
            vb0[s][0] = *(const half8*)(pBk);
            vb0[s][1] = *(const half8*)(pBk + 256);
            const _Float16* pBk1 = pB + ((size_t)2 + s) * 16384;
            vb1[s][0] = *(const half8*)(pBk1);
            vb1[s][1] = *(const half8*)(pBk1 + 256);
        }
    }

    // ---- main: kb = 0..123 (period-4 buffer rotation) ----
    for (int it = 0; it < 31; it++) {
        const int kb = it * 4;
        K1P(kb + 0, 0, vb0, vb2, rA0, rA1, true, true)
        K1P(kb + 1, 1, vb1, vb3, rA1, rA0, true, true)
        K1P(kb + 2, 0, vb2, vb0, rA0, rA1, true, true)
        K1P(kb + 3, 1, vb3, vb1, rA1, rA0, true, true)
    }
    // ---- epilogue: kb = 124..127 ----
    K1P(124, 0, vb0, vb2, rA0, rA1, true, true)
    K1P(125, 1, vb1, vb3, rA1, rA0, true, true)
    K1P(126, 0, vb2, vb0, rA0, rA1, false, true)
    K1P(127, 1, vb3, vb1, rA1, rA0, false, false)

#pragma unroll
    for (int mt = 0; mt < 2; mt++)
#pragma unroll
        for (int nt = 0; nt < 2; nt++) {
#pragma unroll
            for (int r = 0; r < 16; r++) {
                float val = acc[mt][nt][r];
                float oth = __shfl_xor(val, 1, 64);
                if (!(l & 1)) {
                    float pw = fmaf(val, val, fmaf(oth, oth, 1e-14f));
                    int m = m0 + wm + mt * 32 + 4 * qf + (r & 3) + 8 * (r >> 2);
                    int n = n0 + wn + nt * 32 + ml;
                    zxb[m * 512 + (n >> 1)] = f2bf(logf(pw));
                }
            }
        }
}

// ---------------- K2: fused conv1+conv2, chunked-dx (3), y-tile 64 ----------------
// grid (4 yt, 128 b), 4 waves. LDS: zl dbuf (2x3dx x 4 copies x 272) + h1l (3dx).
// PROVEN 137.4 us version (round-0/2/5/7/9/10): (256,2), w1b input, plain conv2.
// FROZEN. Do NOT hand-pipeline conv2 regs (r6: -20us), split waves/tiles
// (r1/r3: -90us), or bundle bounds/setprio/w1-fold (r4: -10us).
#define ZPITCH 272
__global__ __launch_bounds__(256, 2)
void k2_mfma(const ushort* __restrict__ zxb, const ushort* __restrict__ w1b,
             const ushort* __restrict__ w2c, ushort* __restrict__ h2b) {
    __shared__ ushort zl[2 * 3 * 4 * ZPITCH];   // 13,056 B
    __shared__ ushort h1l[3 * 16 * 64 * 8];     // 49,152 B
    const int t  = threadIdx.x;
    const int yt = blockIdx.x;      // 0..3
    const int b  = blockIdx.y;
    const int y0 = yt * 64;
    const int w  = t >> 6;
    const int l  = t & 63;
    const int yy = l & 31;
    const int q  = l >> 5;

    // persistent conv1 A-frags (w1): wave w owns k2 in [32w, 32w+32)
    s8v w1f[8];
    {
        const ushort* wp = w1b + (32 * w + yy) * 128 + 8 * q;
#pragma unroll
        for (int ks = 0; ks < 8; ks++)
            w1f[ks] = *(const s8v*)(wp + 16 * ks);
    }

    f16v acc[2][2];
#pragma unroll
    for (int mt = 0; mt < 2; mt++)
#pragma unroll
        for (int nt = 0; nt < 2; nt++)
#pragma unroll
            for (int r = 0; r < 16; r++) acc[mt][nt][r] = 0.f;

    // ---- initial stage: chunk 0 -> buf 0 ----
    {
        const int nq = 3 * 4 * 62;
        for (int idx = t; idx < nq; idx += 256) {
            int iq = idx % 62;
            int dc = idx / 62;
            int c = dc & 3, d = dc >> 2;
            const ushort* src = zxb + ((b * 25 + d) << 9);
            int gg = 2 * y0 + 2 * c + 4 * iq;
            ushort* dst = zl + (d * 4 + c) * ZPITCH + 4 * iq;
#pragma unroll
            for (int u = 0; u < 4; u++) {
                int g = gg + u;
                dst[u] = (g < 512) ? src[g] : (ushort)0;
            }
        }
    }

    for (int ch = 0; ch < 9; ch++) {
        const int p  = ch & 1;
        const int nd = (ch == 8) ? 1 : 3;
        __syncthreads();   // zl[p] staged, h1l free (prev conv2 done)

        // ---- prefetch loads for chunk ch+1 into regs ----
        ushort pv[12];
        int nq2 = 0;
        if (ch < 8) {
            const int nd2 = (ch == 7) ? 1 : 3;
            nq2 = nd2 * 4 * 62;
#pragma unroll
            for (int r = 0; r < 3; r++) {
                int idx = t + r * 256;
                if (idx < nq2) {
                    int iq = idx % 62;
                    int dc = idx / 62;
                    int c = dc & 3, d = dc >> 2;
                    const ushort* src = zxb + ((b * 25 + (ch + 1) * 3 + d) << 9);
                    int gg = 2 * y0 + 2 * c + 4 * iq;
#pragma unroll
                    for (int u = 0; u < 4; u++) {
                        int g = gg + u;
                        pv[r * 4 + u] = (g < 512) ? src[g] : (ushort)0;
                    }
                }
            }
        }

        // ---- conv1: h1[d][k2][ye] for this chunk ----
        for (int d = 0; d < nd; d++) {
            const int zb = (p * 3 + d) * 4;
#pragma unroll
            for (int nt = 0; nt < 2; nt++) {
                const int ye = nt * 32 + yy;
                const ushort* zp = zl + (zb + (ye & 3)) * ZPITCH + 8 * (ye >> 2) + 8 * q;
                f16v a1;
#pragma unroll
                for (int r = 0; r < 16; r++) a1[r] = 0.f;
#pragma unroll
                for (int ks = 0; ks < 8; ks++) {
                    s8v bf = *(const s8v*)(zp + 16 * ks);
                    a1 = __builtin_amdgcn_mfma_f32_32x32x16_bf16(w1f[ks], bf, a1, 0, 0, 0);
                }
                // relu + pack: k2 = 32w + 8g + 4q + r  -> h1l[d][4w+g][ye][4q+r]
#pragma unroll
                for (int g = 0; g < 4; g++) {
                    unsigned p0 = (unsigned)f2bf(fmaxf(a1[4 * g + 0], 0.f))
                                | ((unsigned)f2bf(fmaxf(a1[4 * g + 1], 0.f)) << 16);
                    unsigned p1 = (unsigned)f2bf(fmaxf(a1[4 * g + 2], 0.f))
                                | ((unsigned)f2bf(fmaxf(a1[4 * g + 3], 0.f)) << 16);
                    unsigned* dst = (unsigned*)(h1l + (((d * 16 + 4 * w + g) * 64) + ye) * 8 + 4 * q);
                    dst[0] = p0; dst[1] = p1;
                }
            }
        }

        // ---- write prefetched zl[1-p] ----
        if (ch < 8) {
#pragma unroll
            for (int r = 0; r < 3; r++) {
                int idx = t + r * 256;
                if (idx < nq2) {
                    int iq = idx % 62;
                    int dc = idx / 62;
                    int c = dc & 3, d = dc >> 2;
                    ushort* dst = zl + (((1 - p) * 3 + d) * 4 + c) * ZPITCH + 4 * iq;
#pragma unroll
                    for (int u = 0; u < 4; u++) dst[u] = pv[r * 4 + u];
                }
            }
        }

        __syncthreads();   // h1l ready

        // ---- conv2: acc[mt][nt] += w2[k3][dx,k2] * h1 ----
        for (int d = 0; d < nd; d++) {
            const int dxa = ch * 3 + d;
            const ushort* ap = w2c + (size_t)(64 * w + yy) * 3200 + dxa * 128 + 8 * q;
#pragma unroll
            for (int ks = 0; ks < 8; ks++) {
                s8v a0 = *(const s8v*)(ap + 16 * ks);
                s8v a1f = *(const s8v*)(ap + (size_t)32 * 3200 + 16 * ks);
#pragma unroll
                for (int nt = 0; nt < 2; nt++) {
                    s8v hb = *(const s8v*)(h1l + (((d * 16 + 2 * ks + q) * 64) + nt * 32 + yy) * 8);
                    acc[0][nt] = __builtin_amdgcn_mfma_f32_32x32x16_bf16(a0, hb, acc[0][nt], 0, 0, 0);
                    acc[1][nt] = __builtin_amdgcn_mfma_f32_32x32x16_bf16(a1f, hb, acc[1][nt], 0, 0, 0);
                }
            }
        }
    }

    // ---- epilogue: store h2b (relu) ----
#pragma unroll
    for (int mt = 0; mt < 2; mt++)
#pragma unroll
        for (int nt = 0; nt < 2; nt++) {
            int y = y0 + nt * 32 + yy;
            if (y < 193) {
#pragma unroll
                for (int r = 0; r < 16; r++) {
                    int k3 = 64 * w + 32 * mt + (r & 3) + 8 * (r >> 2) + 4 * q;
                    h2b[(b * 256 + k3) * 193 + y] = f2bf(fmaxf(acc[mt][nt][r], 0.f));
                }
            }
        }
}

// ---------------- K4 v2: LDS-staged y partials via bf16 MFMA, 193-way k-split --
// Old k4 loaded fragments directly from global in fragment layout: lane ml at
// 98KB row stride -> every s8v load = 64 scattered 16B transactions, mostly
// HBM-miss (h2b written cross-XCD), 1 wave/SIMD to hide it. Now: stage the
// block's h2b/bb tiles (64 KB each, rows contiguous: addr = row*49408 + col)
// into LDS with coalesced 16B loads, read fragments from LDS (row pitch 264
// ushorts = 528B: 16B-aligned, 4-dword bank slots at floor). Same MFMA order
// -> bit-identical. 135 KB LDS; grid 193 < 256 CUs so 1 block/CU regardless.
__global__ __launch_bounds__(256)
void k4_mfma(const ushort* __restrict__ h2b, const ushort* __restrict__ bb,
             float* __restrict__ part) {
    __shared__ ushort hs[128][264];   // 67,584 B
    __shared__ ushort bs[128][264];   // 67,584 B
    const int t = threadIdx.x, w = t >> 6, l = t & 63;
    const int s = blockIdx.x;
    const int kb = s * 256;
    const int qf = l >> 5;
    const int ml = l & 31;

    // ---- coalesced stage: 128 rows x 256 ushorts (32 x 16B chunks per row) ----
    for (int i = t; i < 4096; i += 256) {
        int row = i >> 5;
        int off = (i & 31) * 8;
        *(s8v*)(&hs[row][off]) = *(const s8v*)(h2b + (size_t)row * 49408 + kb + off);
        *(s8v*)(&bs[row][off]) = *(const s8v*)(bb  + (size_t)row * 49408 + kb + off);
    }
    __syncthreads();

    f16v acc[4];
#pragma unroll
    for (int nt = 0; nt < 4; nt++)
#pragma unroll
        for (int r = 0; r < 16; r++) acc[nt][r] = 0.f;

#pragma unroll 4
    for (int ks = 0; ks < 16; ks++) {
        s8v af = *(const s8v*)(&hs[w * 32 + ml][qf * 8 + ks * 16]);
#pragma unroll
        for (int nt = 0; nt < 4; nt++) {
            s8v bf = *(const s8v*)(&bs[nt * 32 + ml][qf * 8 + ks * 16]);
            acc[nt] = __builtin_amdgcn_mfma_f32_32x32x16_bf16(af, bf, acc[nt], 0, 0, 0);
        }
    }
    float* pp = part + (size_t)s * 16384;
#pragma unroll
    for (int nt = 0; nt < 4; nt++)
#pragma unroll
        for (int r = 0; r < 16; r++) {
            int m = w * 32 + 4 * qf + (r & 3) + 8 * (r >> 2);
            pp[m * 128 + nt * 32 + ml] = acc[nt][r];
        }
}

// ---------------- K5: reduce 193 partials (256 blocks, 4-way k-split) ----------------
__global__ __launch_bounds__(256)
void k5_red(const float* __restrict__ part, float* __restrict__ out) {
    __shared__ float red[256];
    const int t  = threadIdx.x;
    const int io = t & 63;
    const int kq = t >> 6;
    const int i  = blockIdx.x * 64 + io;
    float s = 0.f;
#pragma unroll 4
    for (int k = kq; k < 193; k += 4) s += part[(size_t)k * 16384 + i];
    red[t] = s;
    __syncthreads();
    if (t < 64)
        out[blockIdx.x * 64 + t] = (red[t] + red[t + 64]) + (red[t + 128] + red[t + 192]);
}

extern "C" void kernel_launch(void* const* d_in, const int* in_sizes, int n_in,
                              void* d_out, int out_size, void* d_ws, size_t ws_size,
                              hipStream_t stream) {
    const float* x    = (const float*)d_in[0];
    const float* filt = (const float*)d_in[1];
    const float* w1   = (const float*)d_in[2];
    const float* w2   = (const float*)d_in[3];
    const float* beta = (const float*)d_in[4];
    float* out = (float*)d_out;

    char* ws = (char*)d_ws;
    ushort*   zxb  = (ushort*)(ws + 0);
    ushort*   h2b  = (ushort*)(ws + 3276800);
    ushort*   w1b  = (ushort*)(ws + 15921152);
    ushort*   w2c  = (ushort*)(ws + 15953920);
    ushort*   bb   = (ushort*)(ws + 17592320);
    _Float16* xh   = (_Float16*)(ws + 30240768);
    _Float16* fB   = (_Float16*)(ws + 34435072);
    float*    part = (float*)(ws + 30240768);

    k0all<<<2048, 256, 0, stream>>>(x, filt, w1, w2, beta, xh, fB, w1b, w2c, bb);
    k1_mfma<<<dim3(25, 8), 256, 0, stream>>>(xh, fB, zxb);
    k2_mfma<<<dim3(4, 128), 256, 0, stream>>>(zxb, w1b, w2c, h2b);
    k4_mfma<<<193, 256, 0, stream>>>(h2b, bb, part);
    k5_red<<<256, 256, 0, stream>>>(part, out);
}